// Round 18
// baseline (875.612 us; speedup 1.0000x reference)
//
#include <hip/hip_runtime.h>
#include <math.h>

#define DIM 512
#define NSEQ 4096
#define BATCH 4
#define ROWS (BATCH * NSEQ)   // 16384

typedef unsigned long long u64;
typedef unsigned int u32;
typedef unsigned short u16;
typedef __attribute__((ext_vector_type(8))) short bf16x8;
typedef __attribute__((ext_vector_type(4))) float f32x4;

typedef const __attribute__((address_space(1))) void* gas1;
typedef __attribute__((address_space(3))) void* las3;

// ---------------- bf16 helpers (RNE) ----------------
__device__ __forceinline__ u32 to_bf16(float f) {
  u32 x = __float_as_uint(f);
  return (x + 0x7fffu + ((x >> 16) & 1u)) >> 16;
}
__device__ __forceinline__ u32 pk2(float a, float b) {
  return to_bf16(a) | (to_bf16(b) << 16);
}
__device__ __forceinline__ uint4 pk8(float4 a, float4 b) {
  return make_uint4(pk2(a.x, a.y), pk2(a.z, a.w), pk2(b.x, b.y), pk2(b.z, b.w));
}
__device__ __forceinline__ float bf2f(u32 lo16) {
  return __uint_as_float(lo16 << 16);
}

// ---------------- top-N helpers (packed u64 keys) ----------------
__device__ __forceinline__ void insert_top8(u64 (&a)[8], u64 key) {
  if (key <= a[7]) return;
  a[7] = key;
#pragma unroll
  for (int i = 7; i > 0; --i) {
    u64 x = a[i - 1], y = a[i];
    u64 hi = x > y ? x : y;
    u64 lo = x > y ? y : x;
    a[i - 1] = hi;
    a[i] = lo;
  }
}
template<int NN>
__device__ __forceinline__ void insert_topN(u64 (&a)[NN], u64 key) {
  if (key <= a[NN - 1]) return;
  a[NN - 1] = key;
#pragma unroll
  for (int i = NN - 1; i > 0; --i) {
    u64 x = a[i - 1], y = a[i];
    u64 hi = x > y ? x : y;
    u64 lo = x > y ? y : x;
    a[i - 1] = hi;
    a[i] = lo;
  }
}
__device__ __forceinline__ float decode_val(u64 key) {
  u32 ord = (u32)(key >> 32);
  u32 s = (ord & 0x80000000u) ? (ord ^ 0x80000000u) : ~ord;
  return __uint_as_float(s);
}
__device__ __forceinline__ u64 pack_key(float v, int m) {
  u32 sb = __float_as_uint(v);
  u32 ord = sb ^ ((sb >> 31) ? 0xFFFFFFFFu : 0x80000000u);
  return ((u64)ord << 32) | (u32)(~(u32)m);
}

// ---- CU-sum-balanced mapping over 128 sub ids ----
__device__ __forceinline__ int fbal(int sub) {
  const int g = sub >> 5, i = sub & 31;
  return (g == 0) ? i : (g == 1) ? (63 - i) : (g == 2) ? (64 + i) : (127 - i);
}

// -------- weight transpose+convert: y<6: WT[y][n][k] = bf16(W_y[k][n]);
//          y==6: plain bf16 copy of Wm2 (row-major) --------
__global__ __launch_bounds__(256) void wtrans7(const float* __restrict__ Wv,
                                               const float* __restrict__ Wm1,
                                               const float* __restrict__ Wm2,
                                               const float* __restrict__ Wo,
                                               u16* __restrict__ WT) {
  const size_t DD = (size_t)DIM * DIM;
  const int y = blockIdx.y;
  u16* dst = WT + (size_t)y * DD;
  int o = blockIdx.x * 256 + threadIdx.x;
  if (y == 6) {
    const float* s = Wm2 + (size_t)o * 4;
    ((uint2*)dst)[o] = make_uint2(pk2(s[0], s[1]), pk2(s[2], s[3]));
    return;
  }
  const float* src = (y == 0) ? Wv
                   : (y == 1) ? Wm1
                   : (y == 2) ? Wm1 + DD
                   : (y == 3) ? Wm2
                   : (y == 4) ? Wo
                              : Wo + DD;
  int n = o >> 7;
  int k0 = (o & 127) * 4;
  float a0 = src[(size_t)(k0 + 0) * DIM + n];
  float a1 = src[(size_t)(k0 + 1) * DIM + n];
  float a2 = src[(size_t)(k0 + 2) * DIM + n];
  float a3 = src[(size_t)(k0 + 3) * DIM + n];
  ((uint2*)dst)[(n << 7) + (k0 >> 2)] = make_uint2(pk2(a0, a1), pk2(a2, a3));
}

// -------- WT2[n][0:512] = bf16(Wcombf^T), WT2[n][512:1024] = WoBT[n] --------
__global__ __launch_bounds__(256) void wtrans2(const float* __restrict__ Wcombf,
                                               const u16* __restrict__ WoBT,
                                               u16* __restrict__ WT2) {
  int o = blockIdx.x * 256 + threadIdx.x;   // 131072 quads
  int n = o >> 8;
  int k = (o & 255) * 4;
  if (k < 512) {
    float a0 = Wcombf[(size_t)(k + 0) * DIM + n];
    float a1 = Wcombf[(size_t)(k + 1) * DIM + n];
    float a2 = Wcombf[(size_t)(k + 2) * DIM + n];
    float a3 = Wcombf[(size_t)(k + 3) * DIM + n];
    *(uint2*)&WT2[(size_t)n * 1024 + k] = make_uint2(pk2(a0, a1), pk2(a2, a3));
  } else {
    *(uint2*)&WT2[(size_t)n * 1024 + k] = *(const uint2*)&WoBT[(size_t)n * 512 + (k - 512)];
  }
}

// -------- bcomb = bm2 @ Wo_top + bo --------
__global__ void bcomb_k(const float* __restrict__ bm2, const float* __restrict__ Wo,
                        const float* __restrict__ bo, float* __restrict__ bc) {
  int c = blockIdx.x * 256 + threadIdx.x;
  if (c >= DIM) return;
  float s = bo[c];
  for (int k = 0; k < DIM; ++k) s = fmaf(bm2[k], Wo[(size_t)k * DIM + c], s);
  bc[c] = s;
}

// ---------------- bf16 MFMA GEMM (m97 structure), K parametric -------------
// A bf16 [M][lda], WT bf16 [N][K]. Both staged via global_load_lds width=16.
__global__ __launch_bounds__(256, 4) void gemmbf(const u16* __restrict__ A, int lda,
                                                 const u16* __restrict__ WT, int K,
                                                 const float* __restrict__ bias,
                                                 float* C, int ldc) {
  __shared__ u16 As[128 * 32];
  __shared__ u16 Bs[128 * 32];
  const int tid = threadIdx.x;
  const int n0 = blockIdx.x * 128;
  const int m0 = blockIdx.y * 128;
  const int l = tid & 63, lr = l & 15, lu = l >> 4;
  const int wid = tid >> 6, wr = wid >> 1, wc = wid & 1;
  const int lrow = l >> 2, lseg = (l & 3) * 8;
  f32x4 acc[4][4] = {};
  for (int k0 = 0; k0 < K; k0 += 32) {
    __syncthreads();
#pragma unroll
    for (int j = 0; j < 2; ++j) {
      int r0 = wid * 32 + j * 16;
      const u16* sa = A + (size_t)(m0 + r0 + lrow) * lda + k0 + lseg;
      const u16* sb = WT + (size_t)(n0 + r0 + lrow) * K + k0 + lseg;
      __builtin_amdgcn_global_load_lds((gas1)sa, (las3)&As[r0 * 32], 16, 0, 0);
      __builtin_amdgcn_global_load_lds((gas1)sb, (las3)&Bs[r0 * 32], 16, 0, 0);
    }
    __syncthreads();
    bf16x8 af[4], bf_[4];
#pragma unroll
    for (int fr = 0; fr < 4; ++fr) {
      int row = wr * 64 + fr * 16 + lr;
      af[fr] = *(const bf16x8*)&As[row * 32 + lu * 8];
    }
#pragma unroll
    for (int fc = 0; fc < 4; ++fc) {
      int col = wc * 64 + fc * 16 + lr;
      bf_[fc] = *(const bf16x8*)&Bs[col * 32 + lu * 8];
    }
#pragma unroll
    for (int fr = 0; fr < 4; ++fr)
#pragma unroll
      for (int fc = 0; fc < 4; ++fc)
        acc[fr][fc] = __builtin_amdgcn_mfma_f32_16x16x32_bf16(af[fr], bf_[fc], acc[fr][fc], 0, 0, 0);
  }
#pragma unroll
  for (int fr = 0; fr < 4; ++fr)
#pragma unroll
    for (int fc = 0; fc < 4; ++fc) {
      int col = n0 + wc * 64 + fc * 16 + lr;
      float bb = bias ? bias[col] : 0.f;
#pragma unroll
      for (int j = 0; j < 4; ++j) {
        int row = m0 + wr * 64 + fr * 16 + lu * 4 + j;
        C[(size_t)row * ldc + col] = acc[fr][fc][j] + bb;
      }
    }
}

// ================= mega1: qk exact GEMM + v GEMM + Wm1 GEMM ==============
union M1LDS {
  struct { float As[16][132]; float Bs[16][132]; } q;
  struct { u16 As[128 * 32]; u16 Bs[128 * 32]; } g;
};

// exact-chain fp32 q/k body (np-bit-exact), 128x128 tile, 8x8 micro-tile.
__device__ void qk_body(int idx, M1LDS& sh,
                        const float* mu, const float* Wq, const float* bq,
                        const float* Wk, const float* bk,
                        float* Q, float* Kf, u16* Kc) {
  float (&As)[16][132] = sh.q.As;
  float (&Bs)[16][132] = sh.q.Bs;
  const int tid = threadIdx.x;
  const int tx = tid & 15, ty = tid >> 4;
  const int bx = idx & 7;
  const bool isK = bx >= 4;
  const int n0 = (bx & 3) * 128;
  const int m0 = (idx >> 3) * 128;
  const float* W = isK ? Wk : Wq;
  const float* bias = isK ? bk : bq;
  float* C = isK ? Kf : Q;
  const int arow = tid >> 1, ah8 = (tid & 1) * 8;
  const int bkk = tid >> 4, bc8 = (tid & 15) * 8;
  float acc[8][8] = {};
  for (int k0 = 0; k0 < DIM; k0 += 16) {
    float4 a0 = *(const float4*)(mu + (size_t)(m0 + arow) * DIM + (k0 + ah8));
    float4 a1 = *(const float4*)(mu + (size_t)(m0 + arow) * DIM + (k0 + ah8 + 4));
    float4 b0 = *(const float4*)(W + (size_t)(k0 + bkk) * DIM + (n0 + bc8));
    float4 b1 = *(const float4*)(W + (size_t)(k0 + bkk) * DIM + (n0 + bc8 + 4));
    As[ah8 + 0][arow] = a0.x; As[ah8 + 1][arow] = a0.y;
    As[ah8 + 2][arow] = a0.z; As[ah8 + 3][arow] = a0.w;
    As[ah8 + 4][arow] = a1.x; As[ah8 + 5][arow] = a1.y;
    As[ah8 + 6][arow] = a1.z; As[ah8 + 7][arow] = a1.w;
    *(float4*)&Bs[bkk][bc8] = b0;
    *(float4*)&Bs[bkk][bc8 + 4] = b1;
    __syncthreads();
#pragma unroll
    for (int kk = 0; kk < 16; ++kk) {
      float4 av0 = *(const float4*)&As[kk][ty * 8];
      float4 av1 = *(const float4*)&As[kk][ty * 8 + 4];
      float4 bv0 = *(const float4*)&Bs[kk][tx * 8];
      float4 bv1 = *(const float4*)&Bs[kk][tx * 8 + 4];
      float a8[8] = {av0.x, av0.y, av0.z, av0.w, av1.x, av1.y, av1.z, av1.w};
      float b8[8] = {bv0.x, bv0.y, bv0.z, bv0.w, bv1.x, bv1.y, bv1.z, bv1.w};
#pragma unroll
      for (int i = 0; i < 8; ++i)
#pragma unroll
        for (int j = 0; j < 8; ++j)
          acc[i][j] = fmaf(a8[i], b8[j], acc[i][j]);
    }
    __syncthreads();
  }
  float4 bb0 = *(const float4*)(bias + n0 + tx * 8);
  float4 bb1 = *(const float4*)(bias + n0 + tx * 8 + 4);
#pragma unroll
  for (int i = 0; i < 8; ++i) {
    int row = m0 + ty * 8 + i;
#pragma unroll
    for (int jb = 0; jb < 2; ++jb) {
      int col = n0 + tx * 8 + jb * 4;
      float4 bb = jb ? bb1 : bb0;
      float4 o;
      o.x = acc[i][jb * 4 + 0] + bb.x;
      o.y = acc[i][jb * 4 + 1] + bb.y;
      o.z = acc[i][jb * 4 + 2] + bb.z;
      o.w = acc[i][jb * 4 + 3] + bb.w;
      *(float4*)(C + (size_t)row * DIM + col) = o;
      if (isK) {
        int batch = row >> 12, key = row & 4095;
        int kt = key >> 6, kl = key & 63;
        int chunk = col >> 5;
        size_t didx = ((size_t)batch << 21) +
                      ((size_t)((kt * 16 + chunk) * 64 + kl)) * 32 + (col & 31);
        *(uint2*)(Kc + didx) = make_uint2(pk2(o.x, o.y), pk2(o.z, o.w));
      }
    }
  }
}

// fp32-A bf16-C GEMM body (A staged with pk-conversion, B via gload_lds).
__device__ void gemm_f32A(int n0, int m0, M1LDS& sh,
                          const float* A, const u16* WT,
                          const float* bias, u16* Cb, int ldc) {
  u16* As = sh.g.As;
  u16* Bs = sh.g.Bs;
  const int tid = threadIdx.x;
  const int l = tid & 63, lr = l & 15, lu = l >> 4;
  const int wid = tid >> 6, wr = wid >> 1, wc = wid & 1;
  const int lrow = l >> 2, lseg = (l & 3) * 8;
  const int srow = tid >> 1, shalf = tid & 1;
  f32x4 acc[4][4] = {};
  for (int k0 = 0; k0 < 512; k0 += 32) {
    __syncthreads();
    {
      const float4* a4 = (const float4*)(A + (size_t)(m0 + srow) * 512 + k0 + shalf * 16);
      float4 u0 = a4[0], u1 = a4[1], u2 = a4[2], u3 = a4[3];
      int sw = (srow >> 1) & 3;
      *(uint4*)&As[srow * 32 + ((shalf * 2 + 0) ^ sw) * 8] = pk8(u0, u1);
      *(uint4*)&As[srow * 32 + ((shalf * 2 + 1) ^ sw) * 8] = pk8(u2, u3);
    }
#pragma unroll
    for (int j = 0; j < 2; ++j) {
      int r0 = wid * 32 + j * 16;
      const u16* sb = WT + (size_t)(n0 + r0 + lrow) * 512 + k0 + lseg;
      __builtin_amdgcn_global_load_lds((gas1)sb, (las3)&Bs[r0 * 32], 16, 0, 0);
    }
    __syncthreads();
    bf16x8 af[4], bf_[4];
#pragma unroll
    for (int fr = 0; fr < 4; ++fr) {
      int row = wr * 64 + fr * 16 + lr;
      af[fr] = *(const bf16x8*)&As[row * 32 + (lu ^ ((row >> 1) & 3)) * 8];
    }
#pragma unroll
    for (int fc = 0; fc < 4; ++fc) {
      int col = wc * 64 + fc * 16 + lr;
      bf_[fc] = *(const bf16x8*)&Bs[col * 32 + lu * 8];
    }
#pragma unroll
    for (int fr = 0; fr < 4; ++fr)
#pragma unroll
      for (int fc = 0; fc < 4; ++fc)
        acc[fr][fc] = __builtin_amdgcn_mfma_f32_16x16x32_bf16(af[fr], bf_[fc], acc[fr][fc], 0, 0, 0);
  }
#pragma unroll
  for (int fr = 0; fr < 4; ++fr)
#pragma unroll
    for (int fc = 0; fc < 4; ++fc) {
      int col = n0 + wc * 64 + fc * 16 + lr;
      float bb = bias ? bias[col] : 0.f;
#pragma unroll
      for (int j = 0; j < 4; ++j) {
        int row = m0 + wr * 64 + fr * 16 + lu * 4 + j;
        Cb[(size_t)row * ldc + col] = (u16)to_bf16(acc[fr][fc][j] + bb);
      }
    }
}

__global__ __launch_bounds__(256) void mega1(const float* __restrict__ mu,
                                             const float* __restrict__ Wq,
                                             const float* __restrict__ bq,
                                             const float* __restrict__ Wk,
                                             const float* __restrict__ bk,
                                             const u16* __restrict__ WvT,
                                             const float* __restrict__ bv,
                                             const u16* __restrict__ Wm1aT,
                                             float* __restrict__ Q,
                                             float* __restrict__ Kf,
                                             u16* __restrict__ Kc,
                                             u16* __restrict__ V16,
                                             u16* __restrict__ Pair) {
  __shared__ M1LDS sh;
  const int bid = blockIdx.x;     // 2560 = 512 groups x 5 roles (interleaved)
  const int role = bid % 5;
  const int grp = bid / 5;
  if (role < 2) {
    qk_body(grp * 2 + role, sh, mu, Wq, bq, Wk, bk, Q, Kf, Kc);
  } else if (role == 2) {
    gemm_f32A((grp & 3) * 128, (grp >> 2) * 128, sh, mu, WvT, bv, V16, 512);
  } else {
    int i = grp * 2 + (role - 3);
    gemm_f32A((i & 7) * 128, (i >> 3) * 128, sh, mu, Wm1aT, nullptr, Pair, 1024);
  }
}

// ================= mega2: fused attention + silu ==========================
union UA {
  struct { u16 Qs[16 * 512]; u64 cand[256][8]; } s;  // 32 KB (stream phase)
  float Qf32[16][512];                               // 32 KB (rescore phase)
};

__device__ void attn_body(int bid, UA& uA,
                          const float* Qf, const float* Kf, const u16* Kc,
                          const u16* V16, u16* P16,
                          int (&cidx)[16][16], u64 (&exkey)[16][16],
                          float (&psm)[16][8], int (&pidx)[16][8]) {
  const int tid = threadIdx.x;
  const int xcd = bid & 7;
  const int b = xcd >> 1;
  const int par = xcd & 1;
  const int sub = bid >> 3;
  const int qt = 2 * fbal(sub) + par;
  const int n0 = qt * 16;
  const size_t rb = (size_t)b * NSEQ;
  const float SCALE_F = 0.04419417382415922f;

  const int l = tid & 63, lr = l & 15, lu = l >> 4;
  const int wid = tid >> 6;
  const int mbase = lu * 4;

  {
    int row = tid >> 4, part = tid & 15;
    const float4* src = (const float4*)(Qf + ((rb + n0 + row) << 9));
#pragma unroll
    for (int c = 0; c < 4; ++c) {
      int slot = part * 4 + c;
      float4 x = src[slot * 2], y = src[slot * 2 + 1];
      *(uint4*)&uA.s.Qs[row * 512 + (slot ^ (row & 7)) * 8] = pk8(x, y);
    }
  }
  __syncthreads();

  u64 best[8] = {};
  const int nq = n0 + lr;

  const int nkt = (n0 + 16 + 63) >> 6;
  const int lo = (lr * 32) + lu * 8;
  for (int kt = wid; kt < nkt; kt += 4) {
    const int m0 = kt << 6;
    const u16* kb = Kc + ((size_t)b << 21) + (size_t)kt * 32768;
    f32x4 acc[4] = {};
    bf16x8 kcur[4], knxt[4];
#pragma unroll
    for (int fk = 0; fk < 4; ++fk)
      kcur[fk] = *(const bf16x8*)(kb + fk * 512 + lo);
#pragma unroll
    for (int ks = 0; ks < 16; ++ks) {
      if (ks < 15) {
        const u16* cb = kb + (ks + 1) * 2048;
#pragma unroll
        for (int fk = 0; fk < 4; ++fk)
          knxt[fk] = *(const bf16x8*)(cb + fk * 512 + lo);
      }
      bf16x8 qf = *(const bf16x8*)&uA.s.Qs[lr * 512 + ((ks * 4 + lu) ^ (lr & 7)) * 8];
#pragma unroll
      for (int fk = 0; fk < 4; ++fk)
        acc[fk] = __builtin_amdgcn_mfma_f32_16x16x32_bf16(kcur[fk], qf, acc[fk], 0, 0, 0);
      if (ks < 15) {
#pragma unroll
        for (int fk = 0; fk < 4; ++fk) kcur[fk] = knxt[fk];
      }
    }
    if (m0 + 63 <= n0) {
#pragma unroll
      for (int fk = 0; fk < 4; ++fk)
#pragma unroll
        for (int j = 0; j < 4; ++j)
          insert_top8(best, pack_key(acc[fk][j], m0 + fk * 16 + mbase + j));
    } else {
#pragma unroll
      for (int fk = 0; fk < 4; ++fk)
#pragma unroll
        for (int j = 0; j < 4; ++j) {
          int m = m0 + fk * 16 + mbase + j;
          if (m <= nq) insert_top8(best, pack_key(acc[fk][j], m));
        }
    }
  }

  __syncthreads();
#pragma unroll
  for (int i = 0; i < 8; ++i) uA.s.cand[tid][i] = best[i];
  __syncthreads();

  if (tid < 16) {
    u64 mb[16] = {};
    for (int w = 0; w < 4; ++w)
      for (int u = 0; u < 4; ++u) {
        const u64* cl = uA.s.cand[w * 64 + u * 16 + tid];
#pragma unroll
        for (int i = 0; i < 8; ++i) insert_topN<16>(mb, cl[i]);
      }
#pragma unroll
    for (int i = 0; i < 16; ++i)
      cidx[tid][i] = (mb[i] != 0ULL) ? (int)(~(u32)mb[i]) : -1;
  }
  __syncthreads();

  {
    int row = tid >> 4, seg = tid & 15;
    const float4* src = (const float4*)(Qf + ((rb + n0 + row) << 9));
    float4* dst = (float4*)&uA.Qf32[row][0];
#pragma unroll
    for (int c = 0; c < 8; ++c) dst[seg * 8 + c] = src[seg * 8 + c];
  }
  __syncthreads();

  {
    const int g = tid >> 2;
    const int lsub = tid & 3;
    const int qi = g >> 2;
    const int cblk = g & 3;
    const float4* q4 = (const float4*)&uA.Qf32[qi][0];
#pragma unroll
    for (int cc = 0; cc < 4; ++cc) {
      int c = cblk * 4 + cc;
      int ci = cidx[qi][c];
      float4 p = make_float4(0.f, 0.f, 0.f, 0.f);
      if (ci >= 0) {
        const float4* k4 = (const float4*)(Kf + ((rb + ci) << 9));
#pragma unroll 8
        for (int t = 0; t < 32; ++t) {
          float4 kv = k4[4 * t + lsub];
          float4 qv = q4[4 * t + lsub];
          p.x = fmaf(kv.x, qv.x, p.x);
          p.y = fmaf(kv.y, qv.y, p.y);
          p.z = fmaf(kv.z, qv.z, p.z);
          p.w = fmaf(kv.w, qv.w, p.w);
        }
      }
      p.x += __shfl_xor(p.x, 2);
      p.y += __shfl_xor(p.y, 2);
      p.z += __shfl_xor(p.z, 2);
      p.w += __shfl_xor(p.w, 2);
      p.x += __shfl_xor(p.x, 1);
      p.y += __shfl_xor(p.y, 1);
      p.z += __shfl_xor(p.z, 1);
      p.w += __shfl_xor(p.w, 1);
      float rx = p.x + p.z;
      float ry = p.y + p.w;
      float r = rx + ry;
      if (lsub == 0)
        exkey[qi][c] = (ci >= 0) ? pack_key(r * SCALE_F, ci) : 0ULL;
    }
  }
  __syncthreads();

  if (tid < 16) {
    u64 mb[8] = {};
#pragma unroll
    for (int t2 = 0; t2 < 16; ++t2) insert_top8(mb, exkey[tid][t2]);
    float vmax = decode_val(mb[0]);
    float e[8];
#pragma unroll
    for (int i = 0; i < 8; ++i)
      e[i] = (mb[i] != 0ULL) ? expf(decode_val(mb[i]) - vmax) : 0.f;
    float s01 = e[0] + e[1], s23 = e[2] + e[3];
    float s45 = e[4] + e[5], s67 = e[6] + e[7];
    float ssum = (s01 + s23) + (s45 + s67);
#pragma unroll
    for (int i = 0; i < 8; ++i) {
      psm[tid][i] = e[i] / ssum;
      pidx[tid][i] = (mb[i] != 0ULL) ? (int)(~(u32)mb[i]) : 0;
    }
  }
  __syncthreads();

  {  // PV: bf16 V, writes right half of P16 row (cols 512..1023)
    const int qi = tid >> 4, seg = tid & 15;
    float pp[8];
    int ix[8];
#pragma unroll
    for (int i = 0; i < 8; ++i) { pp[i] = psm[qi][i]; ix[i] = pidx[qi][i]; }
    u16* Gb = P16 + ((size_t)(rb + n0 + qi)) * 1024 + 512 + seg * 32;
#pragma unroll
    for (int it = 0; it < 8; ++it) {
      float4 a = make_float4(0.f, 0.f, 0.f, 0.f);
#pragma unroll
      for (int i = 0; i < 8; ++i) {
        uint2 vv = *(const uint2*)(V16 + ((size_t)(rb + ix[i])) * 512 + seg * 32 + it * 4);
        a.x = fmaf(pp[i], bf2f(vv.x & 0xffffu), a.x);
        a.y = fmaf(pp[i], __uint_as_float(vv.x & 0xffff0000u), a.y);
        a.z = fmaf(pp[i], bf2f(vv.y & 0xffffu), a.z);
        a.w = fmaf(pp[i], __uint_as_float(vv.y & 0xffff0000u), a.w);
      }
      *(uint2*)(Gb + it * 4) = make_uint2(pk2(a.x, a.y), pk2(a.z, a.w));
    }
  }
}

// silu over bf16 pair -> bf16 g (left half of P16 rows)
__device__ void silu_body(int sidx, const u16* Pair, const float* bm1, u16* P16) {
#pragma unroll
  for (int t = 0; t < 4; ++t) {
    size_t idx = (size_t)sidx * 1024 + t * 256 + threadIdx.x;
    int r = (int)(idx >> 7);
    int c4 = (int)(idx & 127);
    int n = r & (NSEQ - 1);
    uint2 av = *(const uint2*)&Pair[(size_t)r * 1024 + c4 * 4];
    const float4 bm = ((const float4*)bm1)[c4];
    float bx = bf2f(av.x & 0xffffu) + bm.x;
    float by = __uint_as_float(av.x & 0xffff0000u) + bm.y;
    float bz = bf2f(av.y & 0xffffu) + bm.z;
    float bw = __uint_as_float(av.y & 0xffff0000u) + bm.w;
    float sx = 0.f, sy = 0.f, sz = 0.f, sw = 0.f;
#pragma unroll
    for (int w = 1; w <= 4; ++w) {
      float ex = bx, ey = by, ez = bz, ew = bw;
      if (n >= w) {
        uint2 nb = *(const uint2*)&Pair[(size_t)(r - w) * 1024 + 512 + c4 * 4];
        ex += bf2f(nb.x & 0xffffu);
        ey += __uint_as_float(nb.x & 0xffff0000u);
        ez += bf2f(nb.y & 0xffffu);
        ew += __uint_as_float(nb.y & 0xffff0000u);
      }
      sx += ex / (1.f + expf(-ex));
      sy += ey / (1.f + expf(-ey));
      sz += ez / (1.f + expf(-ez));
      sw += ew / (1.f + expf(-ew));
    }
    *(uint2*)&P16[(size_t)r * 1024 + c4 * 4] =
        make_uint2(pk2(0.25f * sx, 0.25f * sy), pk2(0.25f * sz, 0.25f * sw));
  }
}

__global__ __launch_bounds__(256, 4) void mega2(const float* __restrict__ Qf,
                                                const float* __restrict__ Kf,
                                                const u16* __restrict__ Kc,
                                                const u16* __restrict__ V16,
                                                const u16* __restrict__ Pair,
                                                const float* __restrict__ bm1,
                                                u16* __restrict__ P16) {
  __shared__ UA uA;
  __shared__ int cidx[16][16];
  __shared__ u64 exkey[16][16];
  __shared__ float psm[16][8];
  __shared__ int pidx[16][8];
  const int bid = blockIdx.x;     // 3072 = 1024 groups x 3 roles
  const int role = bid % 3;
  const int grp = bid / 3;
  if (role == 0) {
    attn_body(grp, uA, Qf, Kf, Kc, V16, P16, cidx, exkey, psm, pidx);
  } else {
    silu_body(grp * 2 + (role - 1), Pair, bm1, P16);
  }
}

extern "C" void kernel_launch(void* const* d_in, const int* in_sizes, int n_in,
                              void* d_out, int out_size, void* d_ws, size_t ws_size,
                              hipStream_t stream) {
  const float* mu = (const float*)d_in[0];
  const float* Wq = (const float*)d_in[1];
  const float* bq = (const float*)d_in[2];
  const float* Wk = (const float*)d_in[3];
  const float* bk = (const float*)d_in[4];
  const float* Wv = (const float*)d_in[5];
  const float* bv = (const float*)d_in[6];
  const float* Wm1 = (const float*)d_in[7];
  const float* bm1 = (const float*)d_in[8];
  const float* Wm2 = (const float*)d_in[9];
  const float* bm2 = (const float*)d_in[10];
  const float* Wo = (const float*)d_in[11];
  const float* bo = (const float*)d_in[12];
  float* out = (float*)d_out;

  float* ws = (float*)d_ws;
  const size_t RD = (size_t)ROWS * DIM;
  const size_t DD = (size_t)DIM * DIM;
  float* X1 = ws;                       // q fp32
  float* X2 = X1 + RD;                  // k fp32
  u16* Pair = (u16*)(X2 + RD);          // [16384][1024] bf16 (Wm1 out)
  u16* P16 = Pair + RD * 2;             // [16384][1024] bf16 (g | global)
  u16* Kc = P16 + RD * 2;               // RD bf16 chunk-major K
  u16* V16 = Kc + RD;                   // RD bf16 v
  u16* WT = V16 + RD;                   // 7 x DD bf16
  u16* WvT = WT;
  u16* Wm1aT = WT + DD;                 // [1024][512] contiguous (a then b)
  u16* WoTT = WT + 4 * DD;
  u16* WoBT = WT + 5 * DD;
  u16* Wm216 = WT + 6 * DD;
  u16* WT2 = WT + 7 * DD;               // [512][1024] bf16
  float* Wcombf = (float*)(WT2 + (size_t)512 * 1024);  // DD fp32
  float* bcomb = Wcombf + DD;           // 512 fp32

  dim3 blk(256);

  // prep: weight transposes, local-head fold
  wtrans7<<<dim3(256, 7), blk, 0, stream>>>(Wv, Wm1, Wm2, Wo, WT);
  gemmbf<<<dim3(4, 4), blk, 0, stream>>>(Wm216, 512, WoTT, 512, (const float*)nullptr, Wcombf, 512);
  bcomb_k<<<dim3(2), blk, 0, stream>>>(bm2, Wo, bo, bcomb);
  wtrans2<<<dim3(512), blk, 0, stream>>>(Wcombf, WoBT, WT2);

  // mega1: q/k exact GEMM (VALU) + v GEMM + Wm1 GEMM (MFMA), interleaved
  mega1<<<dim3(2560), blk, 0, stream>>>(mu, Wq, bq, Wk, bk, WvT, bv, Wm1aT,
                                        X1, X2, Kc, V16, Pair);

  // mega2: attention (writes P16 right half) + silu (writes P16 left half)
  mega2<<<dim3(3072), blk, 0, stream>>>(X1, X2, Kc, V16, Pair, bm1, P16);

  // out = [g | global] @ [Wcomb ; WoB] + bcomb   (single K=1024 GEMM)
  gemmbf<<<dim3(4, 128), blk, 0, stream>>>(P16, 1024, WT2, 1024, bcomb, out, 512);
}

// Round 19
// 655.524 us; speedup vs baseline: 1.3357x; 1.3357x over previous
//
#include <hip/hip_runtime.h>
#include <math.h>

#define DIM 512
#define NSEQ 4096
#define BATCH 4
#define ROWS (BATCH * NSEQ)   // 16384

typedef unsigned long long u64;
typedef unsigned int u32;
typedef unsigned short u16;
typedef __attribute__((ext_vector_type(8))) short bf16x8;
typedef __attribute__((ext_vector_type(4))) float f32x4;

typedef const __attribute__((address_space(1))) void* gas1;
typedef __attribute__((address_space(3))) void* las3;

// ---------------- bf16 helpers (RNE) ----------------
__device__ __forceinline__ u32 to_bf16(float f) {
  u32 x = __float_as_uint(f);
  return (x + 0x7fffu + ((x >> 16) & 1u)) >> 16;
}
__device__ __forceinline__ u32 pk2(float a, float b) {
  return to_bf16(a) | (to_bf16(b) << 16);
}
__device__ __forceinline__ uint4 pk8(float4 a, float4 b) {
  return make_uint4(pk2(a.x, a.y), pk2(a.z, a.w), pk2(b.x, b.y), pk2(b.z, b.w));
}

// ---------------- top-N helpers (packed u64 keys) ----------------
// key = ordered_float(score)<<32 | ~index : larger key == larger score; exact
// fp32 ties break toward LOWER index (= np stable top_k). key==0 empty.
__device__ __forceinline__ void insert_top8(u64 (&a)[8], u64 key) {
  if (key <= a[7]) return;
  a[7] = key;
#pragma unroll
  for (int i = 7; i > 0; --i) {
    u64 x = a[i - 1], y = a[i];
    u64 hi = x > y ? x : y;
    u64 lo = x > y ? y : x;
    a[i - 1] = hi;
    a[i] = lo;
  }
}
template<int NN>
__device__ __forceinline__ void insert_topN(u64 (&a)[NN], u64 key) {
  if (key <= a[NN - 1]) return;
  a[NN - 1] = key;
#pragma unroll
  for (int i = NN - 1; i > 0; --i) {
    u64 x = a[i - 1], y = a[i];
    u64 hi = x > y ? x : y;
    u64 lo = x > y ? y : x;
    a[i - 1] = hi;
    a[i] = lo;
  }
}
__device__ __forceinline__ float decode_val(u64 key) {
  u32 ord = (u32)(key >> 32);
  u32 s = (ord & 0x80000000u) ? (ord ^ 0x80000000u) : ~ord;
  return __uint_as_float(s);
}
__device__ __forceinline__ u64 pack_key(float v, int m) {
  u32 sb = __float_as_uint(v);
  u32 ord = sb ^ ((sb >> 31) ? 0xFFFFFFFFu : 0x80000000u);
  return ((u64)ord << 32) | (u32)(~(u32)m);
}

// ---- CU-sum-balanced mapping over 128 sub ids ----
__device__ __forceinline__ int fbal(int sub) {
  const int g = sub >> 5, i = sub & 31;
  return (g == 0) ? i : (g == 1) ? (63 - i) : (g == 2) ? (64 + i) : (127 - i);
}

// ------- fused exact-chain fp32 GEMM for q AND k (np/OpenBLAS-bit-exact) ----
// 128x128 tile, 8x8 micro-tile, K-step 16. bx 0..3 -> Q (bx==0 also emits
// bf16 mu), 4..7 -> K (+ chunk-major Kc).
__global__ __launch_bounds__(256) void gemm64qk(const float* __restrict__ mu,
                                                const float* __restrict__ Wq,
                                                const float* __restrict__ bq,
                                                const float* __restrict__ Wk,
                                                const float* __restrict__ bk,
                                                float* __restrict__ Q,
                                                float* __restrict__ Kf,
                                                u16* __restrict__ Kc,
                                                u16* __restrict__ Mu16) {
  __shared__ float As[16][132];
  __shared__ float Bs[16][132];
  const int tid = threadIdx.x;
  const int tx = tid & 15, ty = tid >> 4;
  const int bx = blockIdx.x;
  const bool isK = bx >= 4;
  const int n0 = (bx & 3) * 128;
  const int m0 = blockIdx.y * 128;
  const float* W = isK ? Wk : Wq;
  const float* bias = isK ? bk : bq;
  float* C = isK ? Kf : Q;
  const int arow = tid >> 1, ah8 = (tid & 1) * 8;
  const int bkk = tid >> 4, bc8 = (tid & 15) * 8;
  float acc[8][8] = {};
  for (int k0 = 0; k0 < DIM; k0 += 16) {
    float4 a0 = *(const float4*)(mu + (size_t)(m0 + arow) * DIM + (k0 + ah8));
    float4 a1 = *(const float4*)(mu + (size_t)(m0 + arow) * DIM + (k0 + ah8 + 4));
    float4 b0 = *(const float4*)(W + (size_t)(k0 + bkk) * DIM + (n0 + bc8));
    float4 b1 = *(const float4*)(W + (size_t)(k0 + bkk) * DIM + (n0 + bc8 + 4));
    if (bx == 0)  // emit bf16 mu once
      *(uint4*)(Mu16 + (size_t)(m0 + arow) * DIM + k0 + ah8) = pk8(a0, a1);
    As[ah8 + 0][arow] = a0.x; As[ah8 + 1][arow] = a0.y;
    As[ah8 + 2][arow] = a0.z; As[ah8 + 3][arow] = a0.w;
    As[ah8 + 4][arow] = a1.x; As[ah8 + 5][arow] = a1.y;
    As[ah8 + 6][arow] = a1.z; As[ah8 + 7][arow] = a1.w;
    *(float4*)&Bs[bkk][bc8] = b0;
    *(float4*)&Bs[bkk][bc8 + 4] = b1;
    __syncthreads();
#pragma unroll
    for (int kk = 0; kk < 16; ++kk) {
      float4 av0 = *(const float4*)&As[kk][ty * 8];
      float4 av1 = *(const float4*)&As[kk][ty * 8 + 4];
      float4 bv0 = *(const float4*)&Bs[kk][tx * 8];
      float4 bv1 = *(const float4*)&Bs[kk][tx * 8 + 4];
      float a8[8] = {av0.x, av0.y, av0.z, av0.w, av1.x, av1.y, av1.z, av1.w};
      float b8[8] = {bv0.x, bv0.y, bv0.z, bv0.w, bv1.x, bv1.y, bv1.z, bv1.w};
#pragma unroll
      for (int i = 0; i < 8; ++i)
#pragma unroll
        for (int j = 0; j < 8; ++j)
          acc[i][j] = fmaf(a8[i], b8[j], acc[i][j]);
    }
    __syncthreads();
  }
  float4 bb0 = *(const float4*)(bias + n0 + tx * 8);
  float4 bb1 = *(const float4*)(bias + n0 + tx * 8 + 4);
#pragma unroll
  for (int i = 0; i < 8; ++i) {
    int row = m0 + ty * 8 + i;
#pragma unroll
    for (int jb = 0; jb < 2; ++jb) {
      int col = n0 + tx * 8 + jb * 4;
      float4 bb = jb ? bb1 : bb0;
      float4 o;
      o.x = acc[i][jb * 4 + 0] + bb.x;
      o.y = acc[i][jb * 4 + 1] + bb.y;
      o.z = acc[i][jb * 4 + 2] + bb.z;
      o.w = acc[i][jb * 4 + 3] + bb.w;
      *(float4*)(C + (size_t)row * DIM + col) = o;
      if (isK) {
        int batch = row >> 12, key = row & 4095;
        int kt = key >> 6, kl = key & 63;
        int chunk = col >> 5;
        size_t didx = ((size_t)batch << 21) +
                      ((size_t)((kt * 16 + chunk) * 64 + kl)) * 32 + (col & 31);
        *(uint2*)(Kc + didx) = make_uint2(pk2(o.x, o.y), pk2(o.z, o.w));
      }
    }
  }
}

// -------- weight transpose+convert: y<6: WT[y][n][k] = bf16(W_y[k][n]);
//          y==6: plain bf16 copy of Wm2 (row-major) --------
__global__ __launch_bounds__(256) void wtrans7(const float* __restrict__ Wv,
                                               const float* __restrict__ Wm1,
                                               const float* __restrict__ Wm2,
                                               const float* __restrict__ Wo,
                                               u16* __restrict__ WT) {
  const size_t DD = (size_t)DIM * DIM;
  const int y = blockIdx.y;
  u16* dst = WT + (size_t)y * DD;
  int o = blockIdx.x * 256 + threadIdx.x;
  if (y == 6) {
    const float* s = Wm2 + (size_t)o * 4;
    ((uint2*)dst)[o] = make_uint2(pk2(s[0], s[1]), pk2(s[2], s[3]));
    return;
  }
  const float* src = (y == 0) ? Wv
                   : (y == 1) ? Wm1
                   : (y == 2) ? Wm1 + DD
                   : (y == 3) ? Wm2
                   : (y == 4) ? Wo
                              : Wo + DD;
  int n = o >> 7;
  int k0 = (o & 127) * 4;
  float a0 = src[(size_t)(k0 + 0) * DIM + n];
  float a1 = src[(size_t)(k0 + 1) * DIM + n];
  float a2 = src[(size_t)(k0 + 2) * DIM + n];
  float a3 = src[(size_t)(k0 + 3) * DIM + n];
  ((uint2*)dst)[(n << 7) + (k0 >> 2)] = make_uint2(pk2(a0, a1), pk2(a2, a3));
}

// -------- WT2[n][0:512] = bf16(Wcombf^T), WT2[n][512:1024] = WoBT[n] --------
__global__ __launch_bounds__(256) void wtrans2(const float* __restrict__ Wcombf,
                                               const u16* __restrict__ WoBT,
                                               u16* __restrict__ WT2) {
  int o = blockIdx.x * 256 + threadIdx.x;   // 131072 quads
  int n = o >> 8;
  int k = (o & 255) * 4;
  if (k < 512) {
    float a0 = Wcombf[(size_t)(k + 0) * DIM + n];
    float a1 = Wcombf[(size_t)(k + 1) * DIM + n];
    float a2 = Wcombf[(size_t)(k + 2) * DIM + n];
    float a3 = Wcombf[(size_t)(k + 3) * DIM + n];
    *(uint2*)&WT2[(size_t)n * 1024 + k] = make_uint2(pk2(a0, a1), pk2(a2, a3));
  } else {
    *(uint2*)&WT2[(size_t)n * 1024 + k] = *(const uint2*)&WoBT[(size_t)n * 512 + (k - 512)];
  }
}

// -------- bcomb = bm2 @ Wo_top + bo --------
__global__ void bcomb_k(const float* __restrict__ bm2, const float* __restrict__ Wo,
                        const float* __restrict__ bo, float* __restrict__ bc) {
  int c = blockIdx.x * 256 + threadIdx.x;
  if (c >= DIM) return;
  float s = bo[c];
  for (int k = 0; k < DIM; ++k) s = fmaf(bm2[k], Wo[(size_t)k * DIM + c], s);
  bc[c] = s;
}

// ---------------- bf16 MFMA GEMM (m97 structure), K parametric -------------
// A bf16 [M][lda], WT bf16 [N][K]. Both staged via global_load_lds width=16.
__global__ __launch_bounds__(256, 4) void gemmbf(const u16* __restrict__ A, int lda,
                                                 const u16* __restrict__ WT, int K,
                                                 const float* __restrict__ bias,
                                                 float* C, int ldc) {
  __shared__ u16 As[128 * 32];
  __shared__ u16 Bs[128 * 32];
  const int tid = threadIdx.x;
  const int n0 = blockIdx.x * 128;
  const int m0 = blockIdx.y * 128;
  const int l = tid & 63, lr = l & 15, lu = l >> 4;
  const int wid = tid >> 6, wr = wid >> 1, wc = wid & 1;
  const int lrow = l >> 2, lseg = (l & 3) * 8;
  f32x4 acc[4][4] = {};
  for (int k0 = 0; k0 < K; k0 += 32) {
    __syncthreads();
#pragma unroll
    for (int j = 0; j < 2; ++j) {
      int r0 = wid * 32 + j * 16;
      const u16* sa = A + (size_t)(m0 + r0 + lrow) * lda + k0 + lseg;
      const u16* sb = WT + (size_t)(n0 + r0 + lrow) * K + k0 + lseg;
      __builtin_amdgcn_global_load_lds((gas1)sa, (las3)&As[r0 * 32], 16, 0, 0);
      __builtin_amdgcn_global_load_lds((gas1)sb, (las3)&Bs[r0 * 32], 16, 0, 0);
    }
    __syncthreads();
    bf16x8 af[4], bf_[4];
#pragma unroll
    for (int fr = 0; fr < 4; ++fr) {
      int row = wr * 64 + fr * 16 + lr;
      af[fr] = *(const bf16x8*)&As[row * 32 + lu * 8];
    }
#pragma unroll
    for (int fc = 0; fc < 4; ++fc) {
      int col = wc * 64 + fc * 16 + lr;
      bf_[fc] = *(const bf16x8*)&Bs[col * 32 + lu * 8];
    }
#pragma unroll
    for (int fr = 0; fr < 4; ++fr)
#pragma unroll
      for (int fc = 0; fc < 4; ++fc)
        acc[fr][fc] = __builtin_amdgcn_mfma_f32_16x16x32_bf16(af[fr], bf_[fc], acc[fr][fc], 0, 0, 0);
  }
#pragma unroll
  for (int fr = 0; fr < 4; ++fr)
#pragma unroll
    for (int fc = 0; fc < 4; ++fc) {
      int col = n0 + wc * 64 + fc * 16 + lr;
      float bb = bias ? bias[col] : 0.f;
#pragma unroll
      for (int j = 0; j < 4; ++j) {
        int row = m0 + wr * 64 + fr * 16 + lu * 4 + j;
        C[(size_t)row * ldc + col] = acc[fr][fc][j] + bb;
      }
    }
}

// -------- local message combine: P16 left half = bf16(g) --------
// P is the interleaved [16384][1024] fp32 pair buffer (A | Bv).
__global__ __launch_bounds__(256) void silu_combine(const float* P,
                                                    const float* bm1,
                                                    u16* P16) {
  size_t idx = (size_t)blockIdx.x * 256 + threadIdx.x;
  int r = (int)(idx >> 7);
  int c4 = (int)(idx & 127);
  int n = r & (NSEQ - 1);
  const float4* P4 = (const float4*)P;
  float4 a = P4[(size_t)r * 256 + c4];
  float4 bm = ((const float4*)bm1)[c4];
  float bx = a.x + bm.x, by = a.y + bm.y, bz = a.z + bm.z, bw = a.w + bm.w;
  float sx = 0.f, sy = 0.f, sz = 0.f, sw = 0.f;
#pragma unroll
  for (int w = 1; w <= 4; ++w) {
    float ex = bx, ey = by, ez = bz, ew = bw;
    if (n >= w) {
      float4 nb = P4[(size_t)(r - w) * 256 + 128 + c4];
      ex += nb.x; ey += nb.y; ez += nb.z; ew += nb.w;
    }
    sx += ex / (1.f + expf(-ex));
    sy += ey / (1.f + expf(-ey));
    sz += ez / (1.f + expf(-ez));
    sw += ew / (1.f + expf(-ew));
  }
  *(uint2*)(P16 + (size_t)r * 1024 + c4 * 4) =
      make_uint2(pk2(0.25f * sx, 0.25f * sy), pk2(0.25f * sz, 0.25f * sw));
}

// ---------------- fused attention: stream + merge + rescore + softmax + PV --
// (R14/R17-proven kernel; PV writes bf16 to P16 right half; setprio on MFMA.)
__global__ __launch_bounds__(256, 4) void attn_fused(const float* __restrict__ Qf,
                                                     const float* __restrict__ Kf,
                                                     const u16* __restrict__ Kc,
                                                     const float* __restrict__ V,
                                                     u16* __restrict__ P16) {
  __shared__ union UA {
    struct { u16 Qs[16 * 512]; u64 cand[256][8]; } s;  // 32 KB (stream phase)
    float Qf32[16][512];                               // 32 KB (rescore phase)
  } uA;
  __shared__ int cidx[16][16];
  __shared__ u64 exkey[16][16];
  __shared__ float psm[16][8];
  __shared__ int pidx[16][8];

  const int tid = threadIdx.x;
  const int bid = blockIdx.x;          // 0..1023
  const int xcd = bid & 7;
  const int b = xcd >> 1;
  const int par = xcd & 1;
  const int sub = bid >> 3;            // 0..127
  const int qt = 2 * fbal(sub) + par;  // 0..255
  const int n0 = qt * 16;
  const size_t rb = (size_t)b * NSEQ;
  const float SCALE_F = 0.04419417382415922f;  // (float)(1/sqrt(512))

  const int l = tid & 63, lr = l & 15, lu = l >> 4;
  const int wid = tid >> 6;
  const int mbase = lu * 4;

  // ---- stage Q block (16 rows x 512) fp32->bf16, swizzled ----
  {
    int row = tid >> 4, part = tid & 15;
    const float4* src = (const float4*)(Qf + ((rb + n0 + row) << 9));
#pragma unroll
    for (int c = 0; c < 4; ++c) {
      int slot = part * 4 + c;
      float4 x = src[slot * 2], y = src[slot * 2 + 1];
      *(uint4*)&uA.s.Qs[row * 512 + (slot ^ (row & 7)) * 8] = pk8(x, y);
    }
  }
  __syncthreads();

  u64 best[8] = {};
  const int nq = n0 + lr;   // this lane's query row

  // ---- barrier-free streaming: wave wid takes 64-key tiles kt=wid,wid+4,..
  const int nkt = (n0 + 16 + 63) >> 6;
  const int lo = (lr * 32) + lu * 8;   // per-lane offset inside a chunk block
  for (int kt = wid; kt < nkt; kt += 4) {
    const int m0 = kt << 6;
    const u16* kb = Kc + ((size_t)b << 21) + (size_t)kt * 32768;  // 16 chunks x 2048
    f32x4 acc[4] = {};
    bf16x8 kcur[4], knxt[4];
#pragma unroll
    for (int fk = 0; fk < 4; ++fk)
      kcur[fk] = *(const bf16x8*)(kb + fk * 512 + lo);
#pragma unroll
    for (int ks = 0; ks < 16; ++ks) {
      if (ks < 15) {
        const u16* cb = kb + (ks + 1) * 2048;
#pragma unroll
        for (int fk = 0; fk < 4; ++fk)
          knxt[fk] = *(const bf16x8*)(cb + fk * 512 + lo);
      }
      bf16x8 qf = *(const bf16x8*)&uA.s.Qs[lr * 512 + ((ks * 4 + lu) ^ (lr & 7)) * 8];
      __builtin_amdgcn_s_setprio(1);
#pragma unroll
      for (int fk = 0; fk < 4; ++fk)
        acc[fk] = __builtin_amdgcn_mfma_f32_16x16x32_bf16(kcur[fk], qf, acc[fk], 0, 0, 0);
      __builtin_amdgcn_s_setprio(0);
      if (ks < 15) {
#pragma unroll
        for (int fk = 0; fk < 4; ++fk) kcur[fk] = knxt[fk];
      }
    }
    // scan (full tiles skip the causal test)
    if (m0 + 63 <= n0) {
#pragma unroll
      for (int fk = 0; fk < 4; ++fk)
#pragma unroll
        for (int j = 0; j < 4; ++j)
          insert_top8(best, pack_key(acc[fk][j], m0 + fk * 16 + mbase + j));
    } else {
#pragma unroll
      for (int fk = 0; fk < 4; ++fk)
#pragma unroll
        for (int j = 0; j < 4; ++j) {
          int m = m0 + fk * 16 + mbase + j;
          if (m <= nq) insert_top8(best, pack_key(acc[fk][j], m));
        }
    }
  }

  __syncthreads();   // all waves done reading Qs
#pragma unroll
  for (int i = 0; i < 8; ++i) uA.s.cand[tid][i] = best[i];
  __syncthreads();

  // ---- merge 16 per-thread lists per query -> bf16 top-16 indices ----
  if (tid < 16) {
    u64 mb[16] = {};
    for (int w = 0; w < 4; ++w)
      for (int u = 0; u < 4; ++u) {
        const u64* cl = uA.s.cand[w * 64 + u * 16 + tid];
#pragma unroll
        for (int i = 0; i < 8; ++i) insert_topN<16>(mb, cl[i]);
      }
#pragma unroll
    for (int i = 0; i < 16; ++i)
      cidx[tid][i] = (mb[i] != 0ULL) ? (int)(~(u32)mb[i]) : -1;
  }
  __syncthreads();

  // ---- re-stage fp32 Q over the dead union ----
  {
    int row = tid >> 4, seg = tid & 15;
    const float4* src = (const float4*)(Qf + ((rb + n0 + row) << 9));
    float4* dst = (float4*)&uA.Qf32[row][0];
#pragma unroll
    for (int c = 0; c < 8; ++c) dst[seg * 8 + c] = src[seg * 8 + c];
  }
  __syncthreads();

  // ---- 4-lane-group exact np-chain rescore ----
  {
    const int g = tid >> 2;       // 0..63
    const int lsub = tid & 3;
    const int qi = g >> 2;        // 0..15
    const int cblk = g & 3;       // 4 candidates per group
    const float4* q4 = (const float4*)&uA.Qf32[qi][0];
#pragma unroll
    for (int cc = 0; cc < 4; ++cc) {
      int c = cblk * 4 + cc;
      int ci = cidx[qi][c];
      float4 p = make_float4(0.f, 0.f, 0.f, 0.f);
      if (ci >= 0) {
        const float4* k4 = (const float4*)(Kf + ((rb + ci) << 9));
#pragma unroll 8
        for (int t = 0; t < 32; ++t) {
          float4 kv = k4[4 * t + lsub];
          float4 qv = q4[4 * t + lsub];
          p.x = fmaf(kv.x, qv.x, p.x);
          p.y = fmaf(kv.y, qv.y, p.y);
          p.z = fmaf(kv.z, qv.z, p.z);
          p.w = fmaf(kv.w, qv.w, p.w);
        }
      }
      // halving tree: s=8 (lane^2), s=4 (lane^1), s=2/1 in-component
      p.x += __shfl_xor(p.x, 2);
      p.y += __shfl_xor(p.y, 2);
      p.z += __shfl_xor(p.z, 2);
      p.w += __shfl_xor(p.w, 2);
      p.x += __shfl_xor(p.x, 1);
      p.y += __shfl_xor(p.y, 1);
      p.z += __shfl_xor(p.z, 1);
      p.w += __shfl_xor(p.w, 1);
      float rx = p.x + p.z;
      float ry = p.y + p.w;
      float r = rx + ry;
      if (lsub == 0)
        exkey[qi][c] = (ci >= 0) ? pack_key(r * SCALE_F, ci) : 0ULL;
    }
  }
  __syncthreads();

  // ---- exact top-8 + np softmax ----
  if (tid < 16) {
    u64 mb[8] = {};
#pragma unroll
    for (int t2 = 0; t2 < 16; ++t2) insert_top8(mb, exkey[tid][t2]);
    float vmax = decode_val(mb[0]);
    float e[8];
#pragma unroll
    for (int i = 0; i < 8; ++i)
      e[i] = (mb[i] != 0ULL) ? expf(decode_val(mb[i]) - vmax) : 0.f;
    float s01 = e[0] + e[1], s23 = e[2] + e[3];
    float s45 = e[4] + e[5], s67 = e[6] + e[7];
    float ssum = (s01 + s23) + (s45 + s67);  // np pairwise-8 tree
#pragma unroll
    for (int i = 0; i < 8; ++i) {
      psm[tid][i] = e[i] / ssum;
      pidx[tid][i] = (mb[i] != 0ULL) ? (int)(~(u32)mb[i]) : 0;
    }
  }
  __syncthreads();

  // ---- PV gather: 16 threads per query, 32 dims each; bf16 to P16 right ----
  {
    const int qi = tid >> 4, seg = tid & 15;
    float pp[8];
    int ix[8];
#pragma unroll
    for (int i = 0; i < 8; ++i) { pp[i] = psm[qi][i]; ix[i] = pidx[qi][i]; }
    const float4* V4 = (const float4*)V;
    u16* Gb = P16 + ((size_t)(rb + n0 + qi)) * 1024 + 512 + seg * 32;
#pragma unroll
    for (int it = 0; it < 8; ++it) {
      float4 a = make_float4(0.f, 0.f, 0.f, 0.f);
#pragma unroll
      for (int i = 0; i < 8; ++i) {
        float4 vv = V4[((rb + ix[i]) << 7) + seg * 8 + it];
        a.x = fmaf(pp[i], vv.x, a.x);
        a.y = fmaf(pp[i], vv.y, a.y);
        a.z = fmaf(pp[i], vv.z, a.z);
        a.w = fmaf(pp[i], vv.w, a.w);
      }
      *(uint2*)(Gb + it * 4) = make_uint2(pk2(a.x, a.y), pk2(a.z, a.w));
    }
  }
}

extern "C" void kernel_launch(void* const* d_in, const int* in_sizes, int n_in,
                              void* d_out, int out_size, void* d_ws, size_t ws_size,
                              hipStream_t stream) {
  const float* mu = (const float*)d_in[0];
  const float* Wq = (const float*)d_in[1];
  const float* bq = (const float*)d_in[2];
  const float* Wk = (const float*)d_in[3];
  const float* bk = (const float*)d_in[4];
  const float* Wv = (const float*)d_in[5];
  const float* bv = (const float*)d_in[6];
  const float* Wm1 = (const float*)d_in[7];
  const float* bm1 = (const float*)d_in[8];
  const float* Wm2 = (const float*)d_in[9];
  const float* bm2 = (const float*)d_in[10];
  const float* Wo = (const float*)d_in[11];
  const float* bo = (const float*)d_in[12];
  float* out = (float*)d_out;

  float* ws = (float*)d_ws;
  const size_t RD = (size_t)ROWS * DIM;
  const size_t DD = (size_t)DIM * DIM;
  float* X1 = ws;            // q fp32  -> later fp32 Wm1 pair (with X2)
  float* X2 = X1 + RD;       // k fp32
  float* X3 = X2 + RD;       // v fp32
  u16* P16 = (u16*)(X3 + RD);          // [16384][1024] bf16 (g | global)
  u16* Kc = P16 + RD * 2;              // RD bf16 chunk-major K
  u16* WT = Kc + RD;                   // 7 x DD bf16
  u16* WvT = WT;
  u16* Wm1aT = WT + DD;                // [1024][512] contiguous (a then b)
  u16* WoTT = WT + 4 * DD;
  u16* WoBT = WT + 5 * DD;
  u16* Wm216 = WT + 6 * DD;
  u16* WT2 = WT + 7 * DD;              // [512][1024] bf16
  float* Wcombf = (float*)(WT2 + (size_t)512 * 1024);  // DD fp32
  float* bcomb = Wcombf + DD;          // 512 fp32
  u16* Mu16 = (u16*)(bcomb + 512);     // RD bf16

  dim3 blk(256);
  dim3 gqk(8, ROWS / 128);
  dim3 gbf(DIM / 128, ROWS / 128);
  dim3 gbf2(2 * DIM / 128, ROWS / 128);

  // prep: weight transposes (+ bf16 Wm2), local-head fold, merged out-weights
  wtrans7<<<dim3(256, 7), blk, 0, stream>>>(Wv, Wm1, Wm2, Wo, WT);
  gemmbf<<<dim3(4, 4), blk, 0, stream>>>(Wm216, 512, WoTT, 512, (const float*)nullptr, Wcombf, 512);
  bcomb_k<<<dim3(2), blk, 0, stream>>>(bm2, Wo, bo, bcomb);
  wtrans2<<<dim3(512), blk, 0, stream>>>(Wcombf, WoBT, WT2);

  // q,k fused exact-chain fp32; emits chunk-major Kc and bf16 mu
  gemm64qk<<<gqk, blk, 0, stream>>>(mu, Wq, bq, Wk, bk, X1, X2, Kc, Mu16);

  // v (bf16 MFMA from bf16 mu) -> fp32 X3
  gemmbf<<<gbf, blk, 0, stream>>>(Mu16, 512, WvT, 512, bv, X3, 512);

  // fused sparse causal attention -> P16 right half (bf16)
  attn_fused<<<dim3(1024), blk, 0, stream>>>(X1, X2, Kc, X3, P16);

  // local path: fused Wm1a|Wm1b gemm -> fp32 pair buffer over X1:X2
  gemmbf<<<gbf2, blk, 0, stream>>>(Mu16, 512, Wm1aT, 512, (const float*)nullptr, X1, 1024);
  silu_combine<<<dim3(ROWS * 128 / 256), blk, 0, stream>>>(X1, bm1, P16);

  // out = [g | global] @ [Wcomb ; WoB] + bcomb   (single K=1024 GEMM)
  gemmbf<<<dim3(4, 128), blk, 0, stream>>>(P16, 1024, WT2, 1024, bcomb, out, 512);
}

// Round 20
// 630.034 us; speedup vs baseline: 1.3898x; 1.0405x over previous
//
#include <hip/hip_runtime.h>
#include <math.h>

#define DIM 512
#define NSEQ 4096
#define BATCH 4
#define ROWS (BATCH * NSEQ)   // 16384

typedef unsigned long long u64;
typedef unsigned int u32;
typedef unsigned short u16;
typedef __attribute__((ext_vector_type(8))) short bf16x8;
typedef __attribute__((ext_vector_type(4))) float f32x4;

typedef const __attribute__((address_space(1))) void* gas1;
typedef __attribute__((address_space(3))) void* las3;

// ---------------- bf16 helpers (RNE) ----------------
__device__ __forceinline__ u32 to_bf16(float f) {
  u32 x = __float_as_uint(f);
  return (x + 0x7fffu + ((x >> 16) & 1u)) >> 16;
}
__device__ __forceinline__ u32 pk2(float a, float b) {
  return to_bf16(a) | (to_bf16(b) << 16);
}
__device__ __forceinline__ uint4 pk8(float4 a, float4 b) {
  return make_uint4(pk2(a.x, a.y), pk2(a.z, a.w), pk2(b.x, b.y), pk2(b.z, b.w));
}
__device__ __forceinline__ float bf2f(u32 lo16) {
  return __uint_as_float(lo16 << 16);
}

// ---------------- top-N helpers (packed u64 keys) ----------------
// key = ordered_float(score)<<32 | ~index : larger key == larger score; exact
// fp32 ties break toward LOWER index (= np stable top_k). key==0 empty.
__device__ __forceinline__ void insert_top8(u64 (&a)[8], u64 key) {
  if (key <= a[7]) return;
  a[7] = key;
#pragma unroll
  for (int i = 7; i > 0; --i) {
    u64 x = a[i - 1], y = a[i];
    u64 hi = x > y ? x : y;
    u64 lo = x > y ? y : x;
    a[i - 1] = hi;
    a[i] = lo;
  }
}
template<int NN>
__device__ __forceinline__ void insert_topN(u64 (&a)[NN], u64 key) {
  if (key <= a[NN - 1]) return;
  a[NN - 1] = key;
#pragma unroll
  for (int i = NN - 1; i > 0; --i) {
    u64 x = a[i - 1], y = a[i];
    u64 hi = x > y ? x : y;
    u64 lo = x > y ? y : x;
    a[i - 1] = hi;
    a[i] = lo;
  }
}
__device__ __forceinline__ float decode_val(u64 key) {
  u32 ord = (u32)(key >> 32);
  u32 s = (ord & 0x80000000u) ? (ord ^ 0x80000000u) : ~ord;
  return __uint_as_float(s);
}
__device__ __forceinline__ u64 pack_key(float v, int m) {
  u32 sb = __float_as_uint(v);
  u32 ord = sb ^ ((sb >> 31) ? 0xFFFFFFFFu : 0x80000000u);
  return ((u64)ord << 32) | (u32)(~(u32)m);
}

// ---- CU-sum-balanced mapping over 128 sub ids ----
__device__ __forceinline__ int fbal(int sub) {
  const int g = sub >> 5, i = sub & 31;
  return (g == 0) ? i : (g == 1) ? (63 - i) : (g == 2) ? (64 + i) : (127 - i);
}

// ------- fused exact-chain fp32 GEMM for q AND k (np/OpenBLAS-bit-exact) ----
// 128x128 tile, 8x8 micro-tile, K-step 16. bx 0..3 -> Q (bx==0 also emits
// bf16 mu), 4..7 -> K (+ chunk-major Kc).
__global__ __launch_bounds__(256) void gemm64qk(const float* __restrict__ mu,
                                                const float* __restrict__ Wq,
                                                const float* __restrict__ bq,
                                                const float* __restrict__ Wk,
                                                const float* __restrict__ bk,
                                                float* __restrict__ Q,
                                                float* __restrict__ Kf,
                                                u16* __restrict__ Kc,
                                                u16* __restrict__ Mu16) {
  __shared__ float As[16][132];
  __shared__ float Bs[16][132];
  const int tid = threadIdx.x;
  const int tx = tid & 15, ty = tid >> 4;
  const int bx = blockIdx.x;
  const bool isK = bx >= 4;
  const int n0 = (bx & 3) * 128;
  const int m0 = blockIdx.y * 128;
  const float* W = isK ? Wk : Wq;
  const float* bias = isK ? bk : bq;
  float* C = isK ? Kf : Q;
  const int arow = tid >> 1, ah8 = (tid & 1) * 8;
  const int bkk = tid >> 4, bc8 = (tid & 15) * 8;
  float acc[8][8] = {};
  for (int k0 = 0; k0 < DIM; k0 += 16) {
    float4 a0 = *(const float4*)(mu + (size_t)(m0 + arow) * DIM + (k0 + ah8));
    float4 a1 = *(const float4*)(mu + (size_t)(m0 + arow) * DIM + (k0 + ah8 + 4));
    float4 b0 = *(const float4*)(W + (size_t)(k0 + bkk) * DIM + (n0 + bc8));
    float4 b1 = *(const float4*)(W + (size_t)(k0 + bkk) * DIM + (n0 + bc8 + 4));
    if (bx == 0)  // emit bf16 mu once
      *(uint4*)(Mu16 + (size_t)(m0 + arow) * DIM + k0 + ah8) = pk8(a0, a1);
    As[ah8 + 0][arow] = a0.x; As[ah8 + 1][arow] = a0.y;
    As[ah8 + 2][arow] = a0.z; As[ah8 + 3][arow] = a0.w;
    As[ah8 + 4][arow] = a1.x; As[ah8 + 5][arow] = a1.y;
    As[ah8 + 6][arow] = a1.z; As[ah8 + 7][arow] = a1.w;
    *(float4*)&Bs[bkk][bc8] = b0;
    *(float4*)&Bs[bkk][bc8 + 4] = b1;
    __syncthreads();
#pragma unroll
    for (int kk = 0; kk < 16; ++kk) {
      float4 av0 = *(const float4*)&As[kk][ty * 8];
      float4 av1 = *(const float4*)&As[kk][ty * 8 + 4];
      float4 bv0 = *(const float4*)&Bs[kk][tx * 8];
      float4 bv1 = *(const float4*)&Bs[kk][tx * 8 + 4];
      float a8[8] = {av0.x, av0.y, av0.z, av0.w, av1.x, av1.y, av1.z, av1.w};
      float b8[8] = {bv0.x, bv0.y, bv0.z, bv0.w, bv1.x, bv1.y, bv1.z, bv1.w};
#pragma unroll
      for (int i = 0; i < 8; ++i)
#pragma unroll
        for (int j = 0; j < 8; ++j)
          acc[i][j] = fmaf(a8[i], b8[j], acc[i][j]);
    }
    __syncthreads();
  }
  float4 bb0 = *(const float4*)(bias + n0 + tx * 8);
  float4 bb1 = *(const float4*)(bias + n0 + tx * 8 + 4);
#pragma unroll
  for (int i = 0; i < 8; ++i) {
    int row = m0 + ty * 8 + i;
#pragma unroll
    for (int jb = 0; jb < 2; ++jb) {
      int col = n0 + tx * 8 + jb * 4;
      float4 bb = jb ? bb1 : bb0;
      float4 o;
      o.x = acc[i][jb * 4 + 0] + bb.x;
      o.y = acc[i][jb * 4 + 1] + bb.y;
      o.z = acc[i][jb * 4 + 2] + bb.z;
      o.w = acc[i][jb * 4 + 3] + bb.w;
      *(float4*)(C + (size_t)row * DIM + col) = o;
      if (isK) {
        int batch = row >> 12, key = row & 4095;
        int kt = key >> 6, kl = key & 63;
        int chunk = col >> 5;
        size_t didx = ((size_t)batch << 21) +
                      ((size_t)((kt * 16 + chunk) * 64 + kl)) * 32 + (col & 31);
        *(uint2*)(Kc + didx) = make_uint2(pk2(o.x, o.y), pk2(o.z, o.w));
      }
    }
  }
}

// -------- weight transpose+convert: y<6: WT[y][n][k] = bf16(W_y[k][n]);
//          y==6: plain bf16 copy of Wm2 (row-major) --------
__global__ __launch_bounds__(256) void wtrans7(const float* __restrict__ Wv,
                                               const float* __restrict__ Wm1,
                                               const float* __restrict__ Wm2,
                                               const float* __restrict__ Wo,
                                               u16* __restrict__ WT) {
  const size_t DD = (size_t)DIM * DIM;
  const int y = blockIdx.y;
  u16* dst = WT + (size_t)y * DD;
  int o = blockIdx.x * 256 + threadIdx.x;
  if (y == 6) {
    const float* s = Wm2 + (size_t)o * 4;
    ((uint2*)dst)[o] = make_uint2(pk2(s[0], s[1]), pk2(s[2], s[3]));
    return;
  }
  const float* src = (y == 0) ? Wv
                   : (y == 1) ? Wm1
                   : (y == 2) ? Wm1 + DD
                   : (y == 3) ? Wm2
                   : (y == 4) ? Wo
                              : Wo + DD;
  int n = o >> 7;
  int k0 = (o & 127) * 4;
  float a0 = src[(size_t)(k0 + 0) * DIM + n];
  float a1 = src[(size_t)(k0 + 1) * DIM + n];
  float a2 = src[(size_t)(k0 + 2) * DIM + n];
  float a3 = src[(size_t)(k0 + 3) * DIM + n];
  ((uint2*)dst)[(n << 7) + (k0 >> 2)] = make_uint2(pk2(a0, a1), pk2(a2, a3));
}

// -------- WT2[n][0:512] = bf16(Wcombf^T), WT2[n][512:1024] = WoBT[n] --------
__global__ __launch_bounds__(256) void wtrans2(const float* __restrict__ Wcombf,
                                               const u16* __restrict__ WoBT,
                                               u16* __restrict__ WT2) {
  int o = blockIdx.x * 256 + threadIdx.x;   // 131072 quads
  int n = o >> 8;
  int k = (o & 255) * 4;
  if (k < 512) {
    float a0 = Wcombf[(size_t)(k + 0) * DIM + n];
    float a1 = Wcombf[(size_t)(k + 1) * DIM + n];
    float a2 = Wcombf[(size_t)(k + 2) * DIM + n];
    float a3 = Wcombf[(size_t)(k + 3) * DIM + n];
    *(uint2*)&WT2[(size_t)n * 1024 + k] = make_uint2(pk2(a0, a1), pk2(a2, a3));
  } else {
    *(uint2*)&WT2[(size_t)n * 1024 + k] = *(const uint2*)&WoBT[(size_t)n * 512 + (k - 512)];
  }
}

// -------- bcomb = bm2 @ Wo_top + bo --------
__global__ void bcomb_k(const float* __restrict__ bm2, const float* __restrict__ Wo,
                        const float* __restrict__ bo, float* __restrict__ bc) {
  int c = blockIdx.x * 256 + threadIdx.x;
  if (c >= DIM) return;
  float s = bo[c];
  for (int k = 0; k < DIM; ++k) s = fmaf(bm2[k], Wo[(size_t)k * DIM + c], s);
  bc[c] = s;
}

// ---------------- bf16 MFMA GEMM (m97 structure), K parametric, fp32 out ----
__global__ __launch_bounds__(256, 4) void gemmbf(const u16* __restrict__ A, int lda,
                                                 const u16* __restrict__ WT, int K,
                                                 const float* __restrict__ bias,
                                                 float* C, int ldc) {
  __shared__ u16 As[128 * 32];
  __shared__ u16 Bs[128 * 32];
  const int tid = threadIdx.x;
  const int n0 = blockIdx.x * 128;
  const int m0 = blockIdx.y * 128;
  const int l = tid & 63, lr = l & 15, lu = l >> 4;
  const int wid = tid >> 6, wr = wid >> 1, wc = wid & 1;
  const int lrow = l >> 2, lseg = (l & 3) * 8;
  f32x4 acc[4][4] = {};
  for (int k0 = 0; k0 < K; k0 += 32) {
    __syncthreads();
#pragma unroll
    for (int j = 0; j < 2; ++j) {
      int r0 = wid * 32 + j * 16;
      const u16* sa = A + (size_t)(m0 + r0 + lrow) * lda + k0 + lseg;
      const u16* sb = WT + (size_t)(n0 + r0 + lrow) * K + k0 + lseg;
      __builtin_amdgcn_global_load_lds((gas1)sa, (las3)&As[r0 * 32], 16, 0, 0);
      __builtin_amdgcn_global_load_lds((gas1)sb, (las3)&Bs[r0 * 32], 16, 0, 0);
    }
    __syncthreads();
    bf16x8 af[4], bf_[4];
#pragma unroll
    for (int fr = 0; fr < 4; ++fr) {
      int row = wr * 64 + fr * 16 + lr;
      af[fr] = *(const bf16x8*)&As[row * 32 + lu * 8];
    }
#pragma unroll
    for (int fc = 0; fc < 4; ++fc) {
      int col = wc * 64 + fc * 16 + lr;
      bf_[fc] = *(const bf16x8*)&Bs[col * 32 + lu * 8];
    }
#pragma unroll
    for (int fr = 0; fr < 4; ++fr)
#pragma unroll
      for (int fc = 0; fc < 4; ++fc)
        acc[fr][fc] = __builtin_amdgcn_mfma_f32_16x16x32_bf16(af[fr], bf_[fc], acc[fr][fc], 0, 0, 0);
  }
#pragma unroll
  for (int fr = 0; fr < 4; ++fr)
#pragma unroll
    for (int fc = 0; fc < 4; ++fc) {
      int col = n0 + wc * 64 + fc * 16 + lr;
      float bb = bias ? bias[col] : 0.f;
#pragma unroll
      for (int j = 0; j < 4; ++j) {
        int row = m0 + wr * 64 + fr * 16 + lu * 4 + j;
        C[(size_t)row * ldc + col] = acc[fr][fc][j] + bb;
      }
    }
}

// ---------------- same GEMM, bf16 output (v and Wm1-pair paths) -------------
__global__ __launch_bounds__(256, 4) void gemmbf_b16(const u16* __restrict__ A, int lda,
                                                     const u16* __restrict__ WT, int K,
                                                     const float* __restrict__ bias,
                                                     u16* Cb, int ldc) {
  __shared__ u16 As[128 * 32];
  __shared__ u16 Bs[128 * 32];
  const int tid = threadIdx.x;
  const int n0 = blockIdx.x * 128;
  const int m0 = blockIdx.y * 128;
  const int l = tid & 63, lr = l & 15, lu = l >> 4;
  const int wid = tid >> 6, wr = wid >> 1, wc = wid & 1;
  const int lrow = l >> 2, lseg = (l & 3) * 8;
  f32x4 acc[4][4] = {};
  for (int k0 = 0; k0 < K; k0 += 32) {
    __syncthreads();
#pragma unroll
    for (int j = 0; j < 2; ++j) {
      int r0 = wid * 32 + j * 16;
      const u16* sa = A + (size_t)(m0 + r0 + lrow) * lda + k0 + lseg;
      const u16* sb = WT + (size_t)(n0 + r0 + lrow) * K + k0 + lseg;
      __builtin_amdgcn_global_load_lds((gas1)sa, (las3)&As[r0 * 32], 16, 0, 0);
      __builtin_amdgcn_global_load_lds((gas1)sb, (las3)&Bs[r0 * 32], 16, 0, 0);
    }
    __syncthreads();
    bf16x8 af[4], bf_[4];
#pragma unroll
    for (int fr = 0; fr < 4; ++fr) {
      int row = wr * 64 + fr * 16 + lr;
      af[fr] = *(const bf16x8*)&As[row * 32 + lu * 8];
    }
#pragma unroll
    for (int fc = 0; fc < 4; ++fc) {
      int col = wc * 64 + fc * 16 + lr;
      bf_[fc] = *(const bf16x8*)&Bs[col * 32 + lu * 8];
    }
#pragma unroll
    for (int fr = 0; fr < 4; ++fr)
#pragma unroll
      for (int fc = 0; fc < 4; ++fc)
        acc[fr][fc] = __builtin_amdgcn_mfma_f32_16x16x32_bf16(af[fr], bf_[fc], acc[fr][fc], 0, 0, 0);
  }
#pragma unroll
  for (int fr = 0; fr < 4; ++fr)
#pragma unroll
    for (int fc = 0; fc < 4; ++fc) {
      int col = n0 + wc * 64 + fc * 16 + lr;
      float bb = bias ? bias[col] : 0.f;
#pragma unroll
      for (int j = 0; j < 4; ++j) {
        int row = m0 + wr * 64 + fr * 16 + lu * 4 + j;
        Cb[(size_t)row * ldc + col] = (u16)to_bf16(acc[fr][fc][j] + bb);
      }
    }
}

// -------- local message combine (bf16 pair in, bf16 g out) --------
// Pair is [16384][1024] bf16: cols 0..511 = A, 512..1023 = Bv.
__global__ __launch_bounds__(256) void silu_combine(const u16* __restrict__ Pair,
                                                    const float* __restrict__ bm1,
                                                    u16* __restrict__ P16) {
  size_t idx = (size_t)blockIdx.x * 256 + threadIdx.x;
  int r = (int)(idx >> 7);
  int c4 = (int)(idx & 127);
  int n = r & (NSEQ - 1);
  uint2 av = *(const uint2*)&Pair[(size_t)r * 1024 + c4 * 4];
  const float4 bm = ((const float4*)bm1)[c4];
  float bx = bf2f(av.x & 0xffffu) + bm.x;
  float by = __uint_as_float(av.x & 0xffff0000u) + bm.y;
  float bz = bf2f(av.y & 0xffffu) + bm.z;
  float bw = __uint_as_float(av.y & 0xffff0000u) + bm.w;
  float sx = 0.f, sy = 0.f, sz = 0.f, sw = 0.f;
#pragma unroll
  for (int w = 1; w <= 4; ++w) {
    float ex = bx, ey = by, ez = bz, ew = bw;
    if (n >= w) {
      uint2 nb = *(const uint2*)&Pair[(size_t)(r - w) * 1024 + 512 + c4 * 4];
      ex += bf2f(nb.x & 0xffffu);
      ey += __uint_as_float(nb.x & 0xffff0000u);
      ez += bf2f(nb.y & 0xffffu);
      ew += __uint_as_float(nb.y & 0xffff0000u);
    }
    sx += ex / (1.f + expf(-ex));
    sy += ey / (1.f + expf(-ey));
    sz += ez / (1.f + expf(-ez));
    sw += ew / (1.f + expf(-ew));
  }
  *(uint2*)(P16 + (size_t)r * 1024 + c4 * 4) =
      make_uint2(pk2(0.25f * sx, 0.25f * sy), pk2(0.25f * sz, 0.25f * sw));
}

// ---------------- fused attention: stream + merge + rescore + softmax + PV --
// (R14/R17-proven; V is bf16 (R18-proven unpack); PV writes P16 right half.)
__global__ __launch_bounds__(256, 4) void attn_fused(const float* __restrict__ Qf,
                                                     const float* __restrict__ Kf,
                                                     const u16* __restrict__ Kc,
                                                     const u16* __restrict__ V16,
                                                     u16* __restrict__ P16) {
  __shared__ union UA {
    struct { u16 Qs[16 * 512]; u64 cand[256][8]; } s;  // 32 KB (stream phase)
    float Qf32[16][512];                               // 32 KB (rescore phase)
  } uA;
  __shared__ int cidx[16][16];
  __shared__ u64 exkey[16][16];
  __shared__ float psm[16][8];
  __shared__ int pidx[16][8];

  const int tid = threadIdx.x;
  const int bid = blockIdx.x;          // 0..1023
  const int xcd = bid & 7;
  const int b = xcd >> 1;
  const int par = xcd & 1;
  const int sub = bid >> 3;            // 0..127
  const int qt = 2 * fbal(sub) + par;  // 0..255
  const int n0 = qt * 16;
  const size_t rb = (size_t)b * NSEQ;
  const float SCALE_F = 0.04419417382415922f;  // (float)(1/sqrt(512))

  const int l = tid & 63, lr = l & 15, lu = l >> 4;
  const int wid = tid >> 6;
  const int mbase = lu * 4;

  // ---- stage Q block (16 rows x 512) fp32->bf16, swizzled ----
  {
    int row = tid >> 4, part = tid & 15;
    const float4* src = (const float4*)(Qf + ((rb + n0 + row) << 9));
#pragma unroll
    for (int c = 0; c < 4; ++c) {
      int slot = part * 4 + c;
      float4 x = src[slot * 2], y = src[slot * 2 + 1];
      *(uint4*)&uA.s.Qs[row * 512 + (slot ^ (row & 7)) * 8] = pk8(x, y);
    }
  }
  __syncthreads();

  u64 best[8] = {};
  const int nq = n0 + lr;   // this lane's query row

  // ---- barrier-free streaming: wave wid takes 64-key tiles kt=wid,wid+4,..
  const int nkt = (n0 + 16 + 63) >> 6;
  const int lo = (lr * 32) + lu * 8;   // per-lane offset inside a chunk block
  for (int kt = wid; kt < nkt; kt += 4) {
    const int m0 = kt << 6;
    const u16* kb = Kc + ((size_t)b << 21) + (size_t)kt * 32768;  // 16 chunks x 2048
    f32x4 acc[4] = {};
    bf16x8 kcur[4], knxt[4];
#pragma unroll
    for (int fk = 0; fk < 4; ++fk)
      kcur[fk] = *(const bf16x8*)(kb + fk * 512 + lo);
#pragma unroll
    for (int ks = 0; ks < 16; ++ks) {
      if (ks < 15) {
        const u16* cb = kb + (ks + 1) * 2048;
#pragma unroll
        for (int fk = 0; fk < 4; ++fk)
          knxt[fk] = *(const bf16x8*)(cb + fk * 512 + lo);
      }
      bf16x8 qf = *(const bf16x8*)&uA.s.Qs[lr * 512 + ((ks * 4 + lu) ^ (lr & 7)) * 8];
      __builtin_amdgcn_s_setprio(1);
#pragma unroll
      for (int fk = 0; fk < 4; ++fk)
        acc[fk] = __builtin_amdgcn_mfma_f32_16x16x32_bf16(kcur[fk], qf, acc[fk], 0, 0, 0);
      __builtin_amdgcn_s_setprio(0);
      if (ks < 15) {
#pragma unroll
        for (int fk = 0; fk < 4; ++fk) kcur[fk] = knxt[fk];
      }
    }
    // scan (full tiles skip the causal test)
    if (m0 + 63 <= n0) {
#pragma unroll
      for (int fk = 0; fk < 4; ++fk)
#pragma unroll
        for (int j = 0; j < 4; ++j)
          insert_top8(best, pack_key(acc[fk][j], m0 + fk * 16 + mbase + j));
    } else {
#pragma unroll
      for (int fk = 0; fk < 4; ++fk)
#pragma unroll
        for (int j = 0; j < 4; ++j) {
          int m = m0 + fk * 16 + mbase + j;
          if (m <= nq) insert_top8(best, pack_key(acc[fk][j], m));
        }
    }
  }

  __syncthreads();   // all waves done reading Qs
#pragma unroll
  for (int i = 0; i < 8; ++i) uA.s.cand[tid][i] = best[i];
  __syncthreads();

  // ---- merge 16 per-thread lists per query -> bf16 top-16 indices ----
  if (tid < 16) {
    u64 mb[16] = {};
    for (int w = 0; w < 4; ++w)
      for (int u = 0; u < 4; ++u) {
        const u64* cl = uA.s.cand[w * 64 + u * 16 + tid];
#pragma unroll
        for (int i = 0; i < 8; ++i) insert_topN<16>(mb, cl[i]);
      }
#pragma unroll
    for (int i = 0; i < 16; ++i)
      cidx[tid][i] = (mb[i] != 0ULL) ? (int)(~(u32)mb[i]) : -1;
  }
  __syncthreads();

  // ---- re-stage fp32 Q over the dead union ----
  {
    int row = tid >> 4, seg = tid & 15;
    const float4* src = (const float4*)(Qf + ((rb + n0 + row) << 9));
    float4* dst = (float4*)&uA.Qf32[row][0];
#pragma unroll
    for (int c = 0; c < 8; ++c) dst[seg * 8 + c] = src[seg * 8 + c];
  }
  __syncthreads();

  // ---- 4-lane-group exact np-chain rescore ----
  {
    const int g = tid >> 2;       // 0..63
    const int lsub = tid & 3;
    const int qi = g >> 2;        // 0..15
    const int cblk = g & 3;       // 4 candidates per group
    const float4* q4 = (const float4*)&uA.Qf32[qi][0];
#pragma unroll
    for (int cc = 0; cc < 4; ++cc) {
      int c = cblk * 4 + cc;
      int ci = cidx[qi][c];
      float4 p = make_float4(0.f, 0.f, 0.f, 0.f);
      if (ci >= 0) {
        const float4* k4 = (const float4*)(Kf + ((rb + ci) << 9));
#pragma unroll 8
        for (int t = 0; t < 32; ++t) {
          float4 kv = k4[4 * t + lsub];
          float4 qv = q4[4 * t + lsub];
          p.x = fmaf(kv.x, qv.x, p.x);
          p.y = fmaf(kv.y, qv.y, p.y);
          p.z = fmaf(kv.z, qv.z, p.z);
          p.w = fmaf(kv.w, qv.w, p.w);
        }
      }
      // halving tree: s=8 (lane^2), s=4 (lane^1), s=2/1 in-component
      p.x += __shfl_xor(p.x, 2);
      p.y += __shfl_xor(p.y, 2);
      p.z += __shfl_xor(p.z, 2);
      p.w += __shfl_xor(p.w, 2);
      p.x += __shfl_xor(p.x, 1);
      p.y += __shfl_xor(p.y, 1);
      p.z += __shfl_xor(p.z, 1);
      p.w += __shfl_xor(p.w, 1);
      float rx = p.x + p.z;
      float ry = p.y + p.w;
      float r = rx + ry;
      if (lsub == 0)
        exkey[qi][c] = (ci >= 0) ? pack_key(r * SCALE_F, ci) : 0ULL;
    }
  }
  __syncthreads();

  // ---- exact top-8 + np softmax ----
  if (tid < 16) {
    u64 mb[8] = {};
#pragma unroll
    for (int t2 = 0; t2 < 16; ++t2) insert_top8(mb, exkey[tid][t2]);
    float vmax = decode_val(mb[0]);
    float e[8];
#pragma unroll
    for (int i = 0; i < 8; ++i)
      e[i] = (mb[i] != 0ULL) ? expf(decode_val(mb[i]) - vmax) : 0.f;
    float s01 = e[0] + e[1], s23 = e[2] + e[3];
    float s45 = e[4] + e[5], s67 = e[6] + e[7];
    float ssum = (s01 + s23) + (s45 + s67);  // np pairwise-8 tree
#pragma unroll
    for (int i = 0; i < 8; ++i) {
      psm[tid][i] = e[i] / ssum;
      pidx[tid][i] = (mb[i] != 0ULL) ? (int)(~(u32)mb[i]) : 0;
    }
  }
  __syncthreads();

  // ---- PV gather: bf16 V (R18-proven unpack); writes P16 right half ----
  {
    const int qi = tid >> 4, seg = tid & 15;
    float pp[8];
    int ix[8];
#pragma unroll
    for (int i = 0; i < 8; ++i) { pp[i] = psm[qi][i]; ix[i] = pidx[qi][i]; }
    u16* Gb = P16 + ((size_t)(rb + n0 + qi)) * 1024 + 512 + seg * 32;
#pragma unroll
    for (int it = 0; it < 8; ++it) {
      float4 a = make_float4(0.f, 0.f, 0.f, 0.f);
#pragma unroll
      for (int i = 0; i < 8; ++i) {
        uint2 vv = *(const uint2*)(V16 + ((size_t)(rb + ix[i])) * 512 + seg * 32 + it * 4);
        a.x = fmaf(pp[i], bf2f(vv.x & 0xffffu), a.x);
        a.y = fmaf(pp[i], __uint_as_float(vv.x & 0xffff0000u), a.y);
        a.z = fmaf(pp[i], bf2f(vv.y & 0xffffu), a.z);
        a.w = fmaf(pp[i], __uint_as_float(vv.y & 0xffff0000u), a.w);
      }
      *(uint2*)(Gb + it * 4) = make_uint2(pk2(a.x, a.y), pk2(a.z, a.w));
    }
  }
}

extern "C" void kernel_launch(void* const* d_in, const int* in_sizes, int n_in,
                              void* d_out, int out_size, void* d_ws, size_t ws_size,
                              hipStream_t stream) {
  const float* mu = (const float*)d_in[0];
  const float* Wq = (const float*)d_in[1];
  const float* bq = (const float*)d_in[2];
  const float* Wk = (const float*)d_in[3];
  const float* bk = (const float*)d_in[4];
  const float* Wv = (const float*)d_in[5];
  const float* bv = (const float*)d_in[6];
  const float* Wm1 = (const float*)d_in[7];
  const float* bm1 = (const float*)d_in[8];
  const float* Wm2 = (const float*)d_in[9];
  const float* bm2 = (const float*)d_in[10];
  const float* Wo = (const float*)d_in[11];
  const float* bo = (const float*)d_in[12];
  float* out = (float*)d_out;

  float* ws = (float*)d_ws;
  const size_t RD = (size_t)ROWS * DIM;
  const size_t DD = (size_t)DIM * DIM;
  float* X1 = ws;                       // q fp32
  float* X2 = X1 + RD;                  // k fp32
  u16* P16 = (u16*)(X2 + RD);           // [16384][1024] bf16 (g | global)
  u16* Pair = P16 + RD * 2;             // [16384][1024] bf16 (Wm1 out)
  u16* V16 = Pair + RD * 2;             // RD bf16 v
  u16* Kc = V16 + RD;                   // RD bf16 chunk-major K
  u16* WT = Kc + RD;                    // 7 x DD bf16
  u16* WvT = WT;
  u16* Wm1aT = WT + DD;                 // [1024][512] contiguous (a then b)
  u16* WoTT = WT + 4 * DD;
  u16* WoBT = WT + 5 * DD;
  u16* Wm216 = WT + 6 * DD;
  u16* WT2 = WT + 7 * DD;               // [512][1024] bf16
  float* Wcombf = (float*)(WT2 + (size_t)512 * 1024);  // DD fp32
  float* bcomb = Wcombf + DD;           // 512 fp32
  u16* Mu16 = (u16*)(bcomb + 512);      // RD bf16

  dim3 blk(256);
  dim3 gqk(8, ROWS / 128);
  dim3 gbf(DIM / 128, ROWS / 128);
  dim3 gbf2(2 * DIM / 128, ROWS / 128);

  // prep: weight transposes (+ bf16 Wm2), local-head fold, merged out-weights
  wtrans7<<<dim3(256, 7), blk, 0, stream>>>(Wv, Wm1, Wm2, Wo, WT);
  gemmbf<<<dim3(4, 4), blk, 0, stream>>>(Wm216, 512, WoTT, 512, (const float*)nullptr, Wcombf, 512);
  bcomb_k<<<dim3(2), blk, 0, stream>>>(bm2, Wo, bo, bcomb);
  wtrans2<<<dim3(512), blk, 0, stream>>>(Wcombf, WoBT, WT2);

  // q,k fused exact-chain fp32; emits chunk-major Kc and bf16 mu
  gemm64qk<<<gqk, blk, 0, stream>>>(mu, Wq, bq, Wk, bk, X1, X2, Kc, Mu16);

  // v (bf16 MFMA from bf16 mu) -> bf16 V16
  gemmbf_b16<<<gbf, blk, 0, stream>>>(Mu16, 512, WvT, 512, bv, V16, 512);

  // fused sparse causal attention -> P16 right half (bf16)
  attn_fused<<<dim3(1024), blk, 0, stream>>>(X1, X2, Kc, V16, P16);

  // local path: fused Wm1a|Wm1b gemm -> bf16 pair buffer
  gemmbf_b16<<<gbf2, blk, 0, stream>>>(Mu16, 512, Wm1aT, 512, (const float*)nullptr, Pair, 1024);
  silu_combine<<<dim3(ROWS * 128 / 256), blk, 0, stream>>>(Pair, bm1, P16);

  // out = [g | global] @ [Wcomb ; WoB] + bcomb   (single K=1024 GEMM)
  gemmbf<<<dim3(4, 128), blk, 0, stream>>>(P16, 1024, WT2, 1024, bcomb, out, 512);
}